// Round 2
// baseline (1032.411 us; speedup 1.0000x reference)
//
#include <hip/hip_runtime.h>
#include <math.h>

#define EMB 2048
#define HD 128
#define SEQ 2048
#define MTOT 8192   // B*S

typedef __bf16 bf16x8 __attribute__((ext_vector_type(8)));
typedef float floatx4 __attribute__((ext_vector_type(4)));

__device__ __forceinline__ unsigned short f2bf(float f) {
    unsigned u = __float_as_uint(f);
    return (unsigned short)((u + 0x7FFFu + ((u >> 16) & 1u)) >> 16);  // RNE
}

// async global->LDS, 16B per lane. LDS dest must be wave-uniform base + lane*16.
__device__ __forceinline__ void gl_lds16(const void* g, void* lds) {
    __builtin_amdgcn_global_load_lds(
        (const __attribute__((address_space(1))) unsigned int*)g,
        (__attribute__((address_space(3))) unsigned int*)lds,
        16, 0, 0);
}

// ---------------- fp32 -> bf16 cast, 4 elems/thread ----------------
__global__ void cast_kernel(const float* __restrict__ src,
                            unsigned short* __restrict__ dst, int n4) {
    int i = blockIdx.x * blockDim.x + threadIdx.x;
    if (i >= n4) return;
    float4 v = reinterpret_cast<const float4*>(src)[i];
    ushort4 o;
    o.x = f2bf(v.x); o.y = f2bf(v.y); o.z = f2bf(v.z); o.w = f2bf(v.w);
    reinterpret_cast<ushort4*>(dst)[i] = o;
}

// ---------------- C[M,N] = A[M,K] * Bw[N,K]^T  (bf16 MFMA) ----------------
// 128x128 block tile, 4 waves (2x2), each wave 64x64 via 4x4 16x16x32 MFMAs.
// Staging via global_load_lds width=16 (m97 pattern: LDS chunk c lands at byte c*16).
template<bool OUT_F32>
__global__ __launch_bounds__(256, 2)
void gemm_bt(const unsigned short* __restrict__ A,
             const unsigned short* __restrict__ Bw,
             void* __restrict__ Cout,
             const float* __restrict__ bias,
             int M, int N, int K)
{
    __shared__ __align__(16) unsigned short sA[128][32];
    __shared__ __align__(16) unsigned short sB[128][32];

    const int tid  = threadIdx.x;
    const int lane = tid & 63;
    const int wave = tid >> 6;
    const int wm = wave >> 1, wn = wave & 1;
    const int col  = lane & 15;
    const int quad = lane >> 4;

    const int m0 = blockIdx.y * 128;
    const int n0 = blockIdx.x * 128;

    floatx4 acc[4][4];
    #pragma unroll
    for (int i = 0; i < 4; i++)
        #pragma unroll
        for (int j = 0; j < 4; j++)
            #pragma unroll
            for (int r = 0; r < 4; r++) acc[i][j][r] = 0.0f;

    for (int k0 = 0; k0 < K; k0 += 32) {
        // chunk c = tid + i*256: row=c>>2, colofs=(c&3)*8; LDS byte addr = c*16 (contiguous)
        #pragma unroll
        for (int i = 0; i < 2; i++) {
            int c = tid + i * 256;
            int row = c >> 2, cc = (c & 3) * 8;
            char* ldsA = (char*)sA + (size_t)(i * 256 + wave * 64) * 16;
            char* ldsB = (char*)sB + (size_t)(i * 256 + wave * 64) * 16;
            gl_lds16(A  + (size_t)(m0 + row) * K + k0 + cc, ldsA);
            gl_lds16(Bw + (size_t)(n0 + row) * K + k0 + cc, ldsB);
        }
        __syncthreads();

        bf16x8 af[4], bfr[4];
        #pragma unroll
        for (int mi = 0; mi < 4; mi++)
            af[mi] = *reinterpret_cast<const bf16x8*>(&sA[wm*64 + mi*16 + col][quad*8]);
        #pragma unroll
        for (int ni = 0; ni < 4; ni++)
            bfr[ni] = *reinterpret_cast<const bf16x8*>(&sB[wn*64 + ni*16 + col][quad*8]);

        #pragma unroll
        for (int mi = 0; mi < 4; mi++)
            #pragma unroll
            for (int ni = 0; ni < 4; ni++)
                acc[mi][ni] = __builtin_amdgcn_mfma_f32_16x16x32_bf16(
                                  af[mi], bfr[ni], acc[mi][ni], 0, 0, 0);
        __syncthreads();
    }

    // epilogue: C/D layout col=lane&15, row=quad*4+reg
    #pragma unroll
    for (int mi = 0; mi < 4; mi++) {
        #pragma unroll
        for (int ni = 0; ni < 4; ni++) {
            #pragma unroll
            for (int r = 0; r < 4; r++) {
                int row = m0 + wm*64 + mi*16 + quad*4 + r;
                int cg  = n0 + wn*64 + ni*16 + col;
                float v = acc[mi][ni][r];
                if (OUT_F32) {
                    float bb = bias ? bias[cg] : 0.0f;
                    reinterpret_cast<float*>(Cout)[(size_t)row * N + cg] = v + bb;
                } else {
                    reinterpret_cast<unsigned short*>(Cout)[(size_t)row * N + cg] = f2bf(v);
                }
            }
        }
    }
}

// ---------------- causal flash attention ----------------
// grid (qb=32, h=16, b=4); block 256 = 4 waves; each wave owns 16 q rows.
__global__ __launch_bounds__(256, 2)
void flash_attn(const unsigned short* __restrict__ Q,
                const unsigned short* __restrict__ Kg,
                const unsigned short* __restrict__ Vg,
                unsigned short* __restrict__ O)
{
    __shared__ __align__(16) unsigned short sK[64][128];   // [key][d]
    __shared__ __align__(16) unsigned short sVt[128][72];  // [d][key], padded
    __shared__ __align__(16) unsigned short sP[4][16 * 64];

    const int tid  = threadIdx.x;
    const int lane = tid & 63;
    const int w    = tid >> 6;
    const int col  = lane & 15;
    const int quad = lane >> 4;

    const int qb = blockIdx.x;
    const int h  = blockIdx.y;
    const int b  = blockIdx.z;

    const size_t rowbase = (size_t)b * SEQ;
    const int hoff = h * HD;

    // preload Q A-fragments: lane holds Q[q=col][k=quad*8+j] per 32-wide k-step
    bf16x8 qf[4];
    {
        const unsigned short* qrow = Q + (rowbase + qb*64 + w*16 + col) * EMB + hoff;
        #pragma unroll
        for (int ks = 0; ks < 4; ks++)
            qf[ks] = *reinterpret_cast<const bf16x8*>(qrow + ks*32 + quad*8);
    }

    floatx4 oacc[8];
    #pragma unroll
    for (int ni = 0; ni < 8; ni++)
        #pragma unroll
        for (int r = 0; r < 4; r++) oacc[ni][r] = 0.0f;
    float m_i[4], l_i[4];
    #pragma unroll
    for (int r = 0; r < 4; r++) { m_i[r] = -1e30f; l_i[r] = 0.0f; }

    const float scl = 0.08838834764831845f;  // 1/sqrt(128)
    unsigned short* sPw = sP[w];

    for (int kt = 0; kt <= qb; kt++) {
        const int k0 = kt * 64;
        // stage K tile [64][128] via global_load_lds (chunk c -> LDS byte c*16, contiguous)
        #pragma unroll
        for (int i = 0; i < 4; i++) {
            int c = tid + i * 256;
            int key = c >> 4, dc = (c & 15) * 8;
            char* ldsK = (char*)sK + (size_t)(i * 256 + w * 64) * 16;
            gl_lds16(Kg + (rowbase + k0 + key) * EMB + hoff + dc, ldsK);
        }
        // stage V transposed [d][key] (scatter -> VGPR path)
        #pragma unroll
        for (int i = 0; i < 4; i++) {
            int c = tid + i * 256;
            int key = c & 63, d0 = (c >> 6) * 8;
            int4 v = *reinterpret_cast<const int4*>(Vg + (rowbase + k0 + key) * EMB + hoff + d0);
            unsigned short tmp[8];
            *reinterpret_cast<int4*>(tmp) = v;
            #pragma unroll
            for (int j = 0; j < 8; j++) sVt[d0 + j][key] = tmp[j];
        }
        __syncthreads();

        // S = Q K^T : 16 q rows x 64 keys
        floatx4 sc[4];
        #pragma unroll
        for (int ni = 0; ni < 4; ni++) {
            #pragma unroll
            for (int r = 0; r < 4; r++) sc[ni][r] = 0.0f;
            #pragma unroll
            for (int ks = 0; ks < 4; ks++) {
                bf16x8 kf = *reinterpret_cast<const bf16x8*>(&sK[ni*16 + col][ks*32 + quad*8]);
                sc[ni] = __builtin_amdgcn_mfma_f32_16x16x32_bf16(qf[ks], kf, sc[ni], 0, 0, 0);
            }
        }

        // online softmax, rows = quad*4+r
        #pragma unroll
        for (int r = 0; r < 4; r++) {
            const int qrow = qb*64 + w*16 + quad*4 + r;
            float sv[4];
            float mx = -1e30f;
            #pragma unroll
            for (int ni = 0; ni < 4; ni++) {
                int key = k0 + ni*16 + col;
                float s = sc[ni][r] * scl;
                s = (key > qrow) ? -1e30f : s;
                sv[ni] = s;
                mx = fmaxf(mx, s);
            }
            #pragma unroll
            for (int off = 1; off < 16; off <<= 1) mx = fmaxf(mx, __shfl_xor(mx, off));
            float mnew  = fmaxf(m_i[r], mx);
            float alpha = __expf(m_i[r] - mnew);
            float rsum = 0.0f;
            #pragma unroll
            for (int ni = 0; ni < 4; ni++) {
                float p = __expf(sv[ni] - mnew);
                rsum += p;
                sPw[(quad*4 + r)*64 + ni*16 + col] = f2bf(p);
            }
            #pragma unroll
            for (int off = 1; off < 16; off <<= 1) rsum += __shfl_xor(rsum, off);
            l_i[r] = l_i[r] * alpha + rsum;
            m_i[r] = mnew;
            #pragma unroll
            for (int ni = 0; ni < 8; ni++) oacc[ni][r] *= alpha;
        }
        __syncthreads();  // drain sP writes (cross-lane) before A-layout reads

        // O += P V : P 16x64 (A-layout from sP), V from sVt (B-layout)
        bf16x8 pf[2];
        #pragma unroll
        for (int ks = 0; ks < 2; ks++)
            pf[ks] = *reinterpret_cast<const bf16x8*>(&sPw[col*64 + ks*32 + quad*8]);
        #pragma unroll
        for (int ni = 0; ni < 8; ni++) {
            #pragma unroll
            for (int ks = 0; ks < 2; ks++) {
                bf16x8 vf = *reinterpret_cast<const bf16x8*>(&sVt[ni*16 + col][ks*32 + quad*8]);
                oacc[ni] = __builtin_amdgcn_mfma_f32_16x16x32_bf16(pf[ks], vf, oacc[ni], 0, 0, 0);
            }
        }
        __syncthreads();  // before next tile overwrites sK/sVt
    }

    // normalize and write ctx in [b,s,h*128+d] layout (bf16)
    #pragma unroll
    for (int ni = 0; ni < 8; ni++) {
        #pragma unroll
        for (int r = 0; r < 4; r++) {
            float v = oacc[ni][r] / l_i[r];
            O[(rowbase + qb*64 + w*16 + quad*4 + r) * EMB + hoff + ni*16 + col] = f2bf(v);
        }
    }
}

extern "C" void kernel_launch(void* const* d_in, const int* in_sizes, int n_in,
                              void* d_out, int out_size, void* d_ws, size_t ws_size,
                              hipStream_t stream)
{
    const float* x  = (const float*)d_in[0];
    const float* Wq = (const float*)d_in[1];
    const float* Wk = (const float*)d_in[2];
    const float* Wv = (const float*)d_in[3];
    const float* Wo = (const float*)d_in[4];
    const float* bo = (const float*)d_in[5];
    float* out = (float*)d_out;

    unsigned short* ws = (unsigned short*)d_ws;
    const size_t XN = (size_t)MTOT * EMB;   // 16,777,216
    const size_t WN = (size_t)EMB * EMB;    //  4,194,304
    unsigned short* xb  = ws;
    unsigned short* wqb = xb  + XN;
    unsigned short* wkb = wqb + WN;
    unsigned short* wvb = wkb + WN;
    unsigned short* wob = wvb + WN;
    unsigned short* qb  = wob + WN;
    unsigned short* kb  = qb  + XN;
    unsigned short* vb  = kb  + XN;
    unsigned short* ctx = xb;  // alias: xb dead after the 3 QKV GEMMs

    // casts
    cast_kernel<<<(int)(XN/4/256), 256, 0, stream>>>(x,  xb,  (int)(XN/4));
    cast_kernel<<<(int)(WN/4/256), 256, 0, stream>>>(Wq, wqb, (int)(WN/4));
    cast_kernel<<<(int)(WN/4/256), 256, 0, stream>>>(Wk, wkb, (int)(WN/4));
    cast_kernel<<<(int)(WN/4/256), 256, 0, stream>>>(Wv, wvb, (int)(WN/4));
    cast_kernel<<<(int)(WN/4/256), 256, 0, stream>>>(Wo, wob, (int)(WN/4));

    dim3 ggrid(EMB / 128, MTOT / 128);  // (16, 64)
    gemm_bt<false><<<ggrid, 256, 0, stream>>>(xb, wqb, qb, nullptr, MTOT, EMB, EMB);
    gemm_bt<false><<<ggrid, 256, 0, stream>>>(xb, wkb, kb, nullptr, MTOT, EMB, EMB);
    gemm_bt<false><<<ggrid, 256, 0, stream>>>(xb, wvb, vb, nullptr, MTOT, EMB, EMB);

    flash_attn<<<dim3(SEQ / 64, 16, 4), 256, 0, stream>>>(qb, kb, vb, ctx);

    gemm_bt<true><<<ggrid, 256, 0, stream>>>(ctx, wob, out, bo, MTOT, EMB, EMB);
}

// Round 3
// 906.547 us; speedup vs baseline: 1.1388x; 1.1388x over previous
//
#include <hip/hip_runtime.h>
#include <math.h>

#define EMB 2048
#define HD 128
#define SEQ 2048
#define MTOT 8192   // B*S

typedef __bf16 bf16x8 __attribute__((ext_vector_type(8)));
typedef float floatx4 __attribute__((ext_vector_type(4)));

__device__ __forceinline__ unsigned short f2bf(float f) {
    unsigned u = __float_as_uint(f);
    return (unsigned short)((u + 0x7FFFu + ((u >> 16) & 1u)) >> 16);  // RNE
}

// async global->LDS, 16B per lane. LDS dest must be wave-uniform base + lane*16.
__device__ __forceinline__ void gl_lds16(const void* g, void* lds) {
    __builtin_amdgcn_global_load_lds(
        (const __attribute__((address_space(1))) unsigned int*)g,
        (__attribute__((address_space(3))) unsigned int*)lds,
        16, 0, 0);
}

// ---------------- fp32 -> bf16 cast, 4 elems/thread ----------------
__global__ void cast_kernel(const float* __restrict__ src,
                            unsigned short* __restrict__ dst, int n4) {
    int i = blockIdx.x * blockDim.x + threadIdx.x;
    if (i >= n4) return;
    float4 v = reinterpret_cast<const float4*>(src)[i];
    ushort4 o;
    o.x = f2bf(v.x); o.y = f2bf(v.y); o.z = f2bf(v.z); o.w = f2bf(v.w);
    reinterpret_cast<ushort4*>(dst)[i] = o;
}

// ---------------- C[M,N] = A[M,K] * Bw[N,K]^T  (bf16 MFMA) ----------------
// 128x128 block tile, 4 waves (2x2), each wave 64x64 via 4x4 16x16x32 MFMAs.
// Staging via global_load_lds width=16 (m97 pattern). Unchanged from R2 (passed).
template<bool OUT_F32>
__global__ __launch_bounds__(256, 2)
void gemm_bt(const unsigned short* __restrict__ A,
             const unsigned short* __restrict__ Bw,
             void* __restrict__ Cout,
             const float* __restrict__ bias,
             int M, int N, int K)
{
    __shared__ __align__(16) unsigned short sA[128][32];
    __shared__ __align__(16) unsigned short sB[128][32];

    const int tid  = threadIdx.x;
    const int lane = tid & 63;
    const int wave = tid >> 6;
    const int wm = wave >> 1, wn = wave & 1;
    const int col  = lane & 15;
    const int quad = lane >> 4;

    const int m0 = blockIdx.y * 128;
    const int n0 = blockIdx.x * 128;

    floatx4 acc[4][4];
    #pragma unroll
    for (int i = 0; i < 4; i++)
        #pragma unroll
        for (int j = 0; j < 4; j++)
            #pragma unroll
            for (int r = 0; r < 4; r++) acc[i][j][r] = 0.0f;

    for (int k0 = 0; k0 < K; k0 += 32) {
        #pragma unroll
        for (int i = 0; i < 2; i++) {
            int c = tid + i * 256;
            int row = c >> 2, cc = (c & 3) * 8;
            char* ldsA = (char*)sA + (size_t)(i * 256 + wave * 64) * 16;
            char* ldsB = (char*)sB + (size_t)(i * 256 + wave * 64) * 16;
            gl_lds16(A  + (size_t)(m0 + row) * K + k0 + cc, ldsA);
            gl_lds16(Bw + (size_t)(n0 + row) * K + k0 + cc, ldsB);
        }
        __syncthreads();

        bf16x8 af[4], bfr[4];
        #pragma unroll
        for (int mi = 0; mi < 4; mi++)
            af[mi] = *reinterpret_cast<const bf16x8*>(&sA[wm*64 + mi*16 + col][quad*8]);
        #pragma unroll
        for (int ni = 0; ni < 4; ni++)
            bfr[ni] = *reinterpret_cast<const bf16x8*>(&sB[wn*64 + ni*16 + col][quad*8]);

        #pragma unroll
        for (int mi = 0; mi < 4; mi++)
            #pragma unroll
            for (int ni = 0; ni < 4; ni++)
                acc[mi][ni] = __builtin_amdgcn_mfma_f32_16x16x32_bf16(
                                  af[mi], bfr[ni], acc[mi][ni], 0, 0, 0);
        __syncthreads();
    }

    #pragma unroll
    for (int mi = 0; mi < 4; mi++) {
        #pragma unroll
        for (int ni = 0; ni < 4; ni++) {
            #pragma unroll
            for (int r = 0; r < 4; r++) {
                int row = m0 + wm*64 + mi*16 + quad*4 + r;
                int cg  = n0 + wn*64 + ni*16 + col;
                float v = acc[mi][ni][r];
                if (OUT_F32) {
                    float bb = bias ? bias[cg] : 0.0f;
                    reinterpret_cast<float*>(Cout)[(size_t)row * N + cg] = v + bb;
                } else {
                    reinterpret_cast<unsigned short*>(Cout)[(size_t)row * N + cg] = f2bf(v);
                }
            }
        }
    }
}

// ---------------- causal flash attention ----------------
// grid (qb=32, h=16, b=4); block 256 = 4 waves; each wave owns 16 q rows.
// R3: sK XOR-swizzled (b128 reads hit the 8-span optimum), sP padded to 72,
//     qb reversed (heavy blocks dispatch first), sP barrier removed (per-wave LDS).
__global__ __launch_bounds__(256, 2)
void flash_attn(const unsigned short* __restrict__ Q,
                const unsigned short* __restrict__ Kg,
                const unsigned short* __restrict__ Vg,
                unsigned short* __restrict__ O)
{
    // sK storage: 16B unit u = key*16 + (dblk ^ (key&7)), dblk = d/8. 16 KB.
    __shared__ __align__(16) unsigned short sK[64 * 128];
    __shared__ __align__(16) unsigned short sVt[128][72];  // [d][key], padded
    __shared__ __align__(16) unsigned short sP[4][16 * 72]; // rows padded to 72

    const int tid  = threadIdx.x;
    const int lane = tid & 63;
    const int w    = tid >> 6;
    const int col  = lane & 15;
    const int quad = lane >> 4;

    const int qb = (SEQ / 64 - 1) - blockIdx.x;   // heavy blocks first
    const int h  = blockIdx.y;
    const int b  = blockIdx.z;

    const size_t rowbase = (size_t)b * SEQ;
    const int hoff = h * HD;

    // preload Q A-fragments: lane holds Q[q=col][k=quad*8+j] per 32-wide k-step
    bf16x8 qf[4];
    {
        const unsigned short* qrow = Q + (rowbase + qb*64 + w*16 + col) * EMB + hoff;
        #pragma unroll
        for (int ks = 0; ks < 4; ks++)
            qf[ks] = *reinterpret_cast<const bf16x8*>(qrow + ks*32 + quad*8);
    }

    floatx4 oacc[8];
    #pragma unroll
    for (int ni = 0; ni < 8; ni++)
        #pragma unroll
        for (int r = 0; r < 4; r++) oacc[ni][r] = 0.0f;
    float m_i[4], l_i[4];
    #pragma unroll
    for (int r = 0; r < 4; r++) { m_i[r] = -1e30f; l_i[r] = 0.0f; }

    const float scl = 0.08838834764831845f;  // 1/sqrt(128)
    unsigned short* sPw = sP[w];

    for (int kt = 0; kt <= qb; kt++) {
        const int k0 = kt * 64;
        // stage K tile via glds; chunk c -> LDS byte c*16 (contract), source
        // picked so storage unit = key*16 + (dblk ^ (key&7)).
        #pragma unroll
        for (int i = 0; i < 4; i++) {
            int c = tid + i * 256;
            int key = c >> 4;
            int dblk = (c & 15) ^ (key & 7);
            char* ldsK = (char*)sK + (size_t)(i * 256 + w * 64) * 16;
            gl_lds16(Kg + (rowbase + k0 + key) * EMB + hoff + dblk * 8, ldsK);
        }
        // stage V transposed [d][key] (scatter -> VGPR path); key==lane -> 2-way free
        #pragma unroll
        for (int i = 0; i < 4; i++) {
            int c = tid + i * 256;
            int key = c & 63, d0 = (c >> 6) * 8;
            int4 v = *reinterpret_cast<const int4*>(Vg + (rowbase + k0 + key) * EMB + hoff + d0);
            unsigned short tmp[8];
            *reinterpret_cast<int4*>(tmp) = v;
            #pragma unroll
            for (int j = 0; j < 8; j++) sVt[d0 + j][key] = tmp[j];
        }
        __syncthreads();

        // S = Q K^T : 16 q rows x 64 keys; swizzled sK read
        floatx4 sc[4];
        #pragma unroll
        for (int ni = 0; ni < 4; ni++) {
            #pragma unroll
            for (int r = 0; r < 4; r++) sc[ni][r] = 0.0f;
            #pragma unroll
            for (int ks = 0; ks < 4; ks++) {
                int u = (ni*16 + col) * 16 + (((ks*4 + quad) ^ (col & 7)));
                bf16x8 kf = *reinterpret_cast<const bf16x8*>(&sK[u * 8]);
                sc[ni] = __builtin_amdgcn_mfma_f32_16x16x32_bf16(qf[ks], kf, sc[ni], 0, 0, 0);
            }
        }

        // online softmax, rows = quad*4+r
        #pragma unroll
        for (int r = 0; r < 4; r++) {
            const int qrow = qb*64 + w*16 + quad*4 + r;
            float sv[4];
            float mx = -1e30f;
            #pragma unroll
            for (int ni = 0; ni < 4; ni++) {
                int key = k0 + ni*16 + col;
                float s = sc[ni][r] * scl;
                s = (key > qrow) ? -1e30f : s;
                sv[ni] = s;
                mx = fmaxf(mx, s);
            }
            #pragma unroll
            for (int off = 1; off < 16; off <<= 1) mx = fmaxf(mx, __shfl_xor(mx, off));
            float mnew  = fmaxf(m_i[r], mx);
            float alpha = __expf(m_i[r] - mnew);
            float rsum = 0.0f;
            #pragma unroll
            for (int ni = 0; ni < 4; ni++) {
                float p = __expf(sv[ni] - mnew);
                rsum += p;
                sPw[(quad*4 + r)*72 + ni*16 + col] = f2bf(p);
            }
            #pragma unroll
            for (int off = 1; off < 16; off <<= 1) rsum += __shfl_xor(rsum, off);
            l_i[r] = l_i[r] * alpha + rsum;
            m_i[r] = mnew;
            #pragma unroll
            for (int ni = 0; ni < 8; ni++) oacc[ni][r] *= alpha;
        }
        // no barrier: sP[w] is wave-private; lgkmcnt orders intra-wave LDS

        // O += P V : P 16x64 (A-layout from sP), V from sVt (B-layout)
        bf16x8 pf[2];
        #pragma unroll
        for (int ks = 0; ks < 2; ks++)
            pf[ks] = *reinterpret_cast<const bf16x8*>(&sPw[col*72 + ks*32 + quad*8]);
        #pragma unroll
        for (int ni = 0; ni < 8; ni++) {
            #pragma unroll
            for (int ks = 0; ks < 2; ks++) {
                bf16x8 vf = *reinterpret_cast<const bf16x8*>(&sVt[ni*16 + col][ks*32 + quad*8]);
                oacc[ni] = __builtin_amdgcn_mfma_f32_16x16x32_bf16(pf[ks], vf, oacc[ni], 0, 0, 0);
            }
        }
        __syncthreads();  // before next tile overwrites sK/sVt
    }

    // normalize and write ctx in [b,s,h*128+d] layout (bf16)
    #pragma unroll
    for (int ni = 0; ni < 8; ni++) {
        #pragma unroll
        for (int r = 0; r < 4; r++) {
            float v = oacc[ni][r] / l_i[r];
            O[(rowbase + qb*64 + w*16 + quad*4 + r) * EMB + hoff + ni*16 + col] = f2bf(v);
        }
    }
}

extern "C" void kernel_launch(void* const* d_in, const int* in_sizes, int n_in,
                              void* d_out, int out_size, void* d_ws, size_t ws_size,
                              hipStream_t stream)
{
    const float* x  = (const float*)d_in[0];
    const float* Wq = (const float*)d_in[1];
    const float* Wk = (const float*)d_in[2];
    const float* Wv = (const float*)d_in[3];
    const float* Wo = (const float*)d_in[4];
    const float* bo = (const float*)d_in[5];
    float* out = (float*)d_out;

    unsigned short* ws = (unsigned short*)d_ws;
    const size_t XN = (size_t)MTOT * EMB;   // 16,777,216
    const size_t WN = (size_t)EMB * EMB;    //  4,194,304
    unsigned short* xb  = ws;
    unsigned short* wqb = xb  + XN;
    unsigned short* wkb = wqb + WN;
    unsigned short* wvb = wkb + WN;
    unsigned short* wob = wvb + WN;
    unsigned short* qb  = wob + WN;
    unsigned short* kb  = qb  + XN;
    unsigned short* vb  = kb  + XN;
    unsigned short* ctx = xb;  // alias: xb dead after the 3 QKV GEMMs

    cast_kernel<<<(int)(XN/4/256), 256, 0, stream>>>(x,  xb,  (int)(XN/4));
    cast_kernel<<<(int)(WN/4/256), 256, 0, stream>>>(Wq, wqb, (int)(WN/4));
    cast_kernel<<<(int)(WN/4/256), 256, 0, stream>>>(Wk, wkb, (int)(WN/4));
    cast_kernel<<<(int)(WN/4/256), 256, 0, stream>>>(Wv, wvb, (int)(WN/4));
    cast_kernel<<<(int)(WN/4/256), 256, 0, stream>>>(Wo, wob, (int)(WN/4));

    dim3 ggrid(EMB / 128, MTOT / 128);  // (16, 64)
    gemm_bt<false><<<ggrid, 256, 0, stream>>>(xb, wqb, qb, nullptr, MTOT, EMB, EMB);
    gemm_bt<false><<<ggrid, 256, 0, stream>>>(xb, wkb, kb, nullptr, MTOT, EMB, EMB);
    gemm_bt<false><<<ggrid, 256, 0, stream>>>(xb, wvb, vb, nullptr, MTOT, EMB, EMB);

    flash_attn<<<dim3(SEQ / 64, 16, 4), 256, 0, stream>>>(qb, kb, vb, ctx);

    gemm_bt<true><<<ggrid, 256, 0, stream>>>(ctx, wob, out, bo, MTOT, EMB, EMB);
}

// Round 4
// 796.050 us; speedup vs baseline: 1.2969x; 1.1388x over previous
//
#include <hip/hip_runtime.h>
#include <math.h>

#define EMB 2048
#define HD 128
#define SEQ 2048
#define MTOT 8192   // B*S

typedef __bf16 bf16x8 __attribute__((ext_vector_type(8)));
typedef float floatx4 __attribute__((ext_vector_type(4)));

__device__ __forceinline__ unsigned short f2bf(float f) {
    unsigned u = __float_as_uint(f);
    return (unsigned short)((u + 0x7FFFu + ((u >> 16) & 1u)) >> 16);  // RNE
}

// async global->LDS, 16B per lane. LDS dest must be wave-uniform base + lane*16.
__device__ __forceinline__ void gl_lds16(const void* g, void* lds) {
    __builtin_amdgcn_global_load_lds(
        (const __attribute__((address_space(1))) unsigned int*)g,
        (__attribute__((address_space(3))) unsigned int*)lds,
        16, 0, 0);
}

// ---------------- fp32 -> bf16 cast, 4 elems/thread ----------------
__global__ void cast_kernel(const float* __restrict__ src,
                            unsigned short* __restrict__ dst, int n4) {
    int i = blockIdx.x * blockDim.x + threadIdx.x;
    if (i >= n4) return;
    float4 v = reinterpret_cast<const float4*>(src)[i];
    ushort4 o;
    o.x = f2bf(v.x); o.y = f2bf(v.y); o.z = f2bf(v.z); o.w = f2bf(v.w);
    reinterpret_cast<ushort4*>(dst)[i] = o;
}

// ---------------- C[M,N] = A[M,K] * Bw[N,K]^T  (bf16 MFMA) ----------------
// 128x128 block tile, 4 waves (2x2), each wave 64x64 via 4x4 16x16x32 MFMAs.
// Staging via global_load_lds width=16 (m97 pattern). Unchanged (verified).
template<bool OUT_F32>
__global__ __launch_bounds__(256, 2)
void gemm_bt(const unsigned short* __restrict__ A,
             const unsigned short* __restrict__ Bw,
             void* __restrict__ Cout,
             const float* __restrict__ bias,
             int M, int N, int K)
{
    __shared__ __align__(16) unsigned short sA[128][32];
    __shared__ __align__(16) unsigned short sB[128][32];

    const int tid  = threadIdx.x;
    const int lane = tid & 63;
    const int wave = tid >> 6;
    const int wm = wave >> 1, wn = wave & 1;
    const int col  = lane & 15;
    const int quad = lane >> 4;

    const int m0 = blockIdx.y * 128;
    const int n0 = blockIdx.x * 128;

    floatx4 acc[4][4];
    #pragma unroll
    for (int i = 0; i < 4; i++)
        #pragma unroll
        for (int j = 0; j < 4; j++)
            #pragma unroll
            for (int r = 0; r < 4; r++) acc[i][j][r] = 0.0f;

    for (int k0 = 0; k0 < K; k0 += 32) {
        #pragma unroll
        for (int i = 0; i < 2; i++) {
            int c = tid + i * 256;
            int row = c >> 2, cc = (c & 3) * 8;
            char* ldsA = (char*)sA + (size_t)(i * 256 + wave * 64) * 16;
            char* ldsB = (char*)sB + (size_t)(i * 256 + wave * 64) * 16;
            gl_lds16(A  + (size_t)(m0 + row) * K + k0 + cc, ldsA);
            gl_lds16(Bw + (size_t)(n0 + row) * K + k0 + cc, ldsB);
        }
        __syncthreads();

        bf16x8 af[4], bfr[4];
        #pragma unroll
        for (int mi = 0; mi < 4; mi++)
            af[mi] = *reinterpret_cast<const bf16x8*>(&sA[wm*64 + mi*16 + col][quad*8]);
        #pragma unroll
        for (int ni = 0; ni < 4; ni++)
            bfr[ni] = *reinterpret_cast<const bf16x8*>(&sB[wn*64 + ni*16 + col][quad*8]);

        #pragma unroll
        for (int mi = 0; mi < 4; mi++)
            #pragma unroll
            for (int ni = 0; ni < 4; ni++)
                acc[mi][ni] = __builtin_amdgcn_mfma_f32_16x16x32_bf16(
                                  af[mi], bfr[ni], acc[mi][ni], 0, 0, 0);
        __syncthreads();
    }

    #pragma unroll
    for (int mi = 0; mi < 4; mi++) {
        #pragma unroll
        for (int ni = 0; ni < 4; ni++) {
            #pragma unroll
            for (int r = 0; r < 4; r++) {
                int row = m0 + wm*64 + mi*16 + quad*4 + r;
                int cg  = n0 + wn*64 + ni*16 + col;
                float v = acc[mi][ni][r];
                if (OUT_F32) {
                    float bb = bias ? bias[cg] : 0.0f;
                    reinterpret_cast<float*>(Cout)[(size_t)row * N + cg] = v + bb;
                } else {
                    reinterpret_cast<unsigned short*>(Cout)[(size_t)row * N + cg] = f2bf(v);
                }
            }
        }
    }
}

// ---------------- causal flash attention, S^T formulation ----------------
// grid (qb=32, h=16, b=4); block 256 = 4 waves; each wave owns 16 q rows.
// R4: compute S^T = K*Q^T (swap MFMA operands) so each lane owns ONE q column:
//     softmax is in-lane + 2 shfls, alpha/m/l are scalars, P written as 4
//     ds_write_b64, PV computed as O^T = V^T * P^T (vf reads unchanged).
__global__ __launch_bounds__(256, 2)
void flash_attn(const unsigned short* __restrict__ Q,
                const unsigned short* __restrict__ Kg,
                const unsigned short* __restrict__ Vg,
                unsigned short* __restrict__ O)
{
    // sK storage: 16B unit u = key*16 + (dblk ^ (key&7)), dblk = d/8. 16 KB.
    __shared__ __align__(16) unsigned short sK[64 * 128];
    __shared__ __align__(16) unsigned short sVt[128][72];   // [d][key], padded
    __shared__ __align__(16) unsigned short sP[4][16 * 72]; // [q][key], padded

    const int tid  = threadIdx.x;
    const int lane = tid & 63;
    const int w    = tid >> 6;
    const int col  = lane & 15;
    const int quad = lane >> 4;

    const int qb = (SEQ / 64 - 1) - blockIdx.x;   // heavy blocks first
    const int h  = blockIdx.y;
    const int b  = blockIdx.z;

    const size_t rowbase = (size_t)b * SEQ;
    const int hoff = h * HD;

    const int qg = qb*64 + w*16 + col;  // this lane's q row (4 quads share it)

    // Q fragments (B-operand for S^T): lane holds Q[q=col][d=ks*32+quad*8+j]
    bf16x8 qf[4];
    {
        const unsigned short* qrow = Q + (rowbase + qg) * EMB + hoff;
        #pragma unroll
        for (int ks = 0; ks < 4; ks++)
            qf[ks] = *reinterpret_cast<const bf16x8*>(qrow + ks*32 + quad*8);
    }

    // O^T accumulator: lane holds O^T[d=ni*16+quad*4+r][q=col]
    floatx4 oacc[8];
    #pragma unroll
    for (int ni = 0; ni < 8; ni++)
        #pragma unroll
        for (int r = 0; r < 4; r++) oacc[ni][r] = 0.0f;
    float m_i = -1e30f, l_i = 0.0f;   // per-lane scalars (one q per lane)

    const float scl = 0.08838834764831845f;  // 1/sqrt(128)
    const int tmask = w*16 + col;            // local key threshold (diag tile)
    unsigned short* sPw = sP[w];

    for (int kt = 0; kt <= qb; kt++) {
        const int k0 = kt * 64;
        // stage K tile via glds; chunk c -> LDS byte c*16, swizzled source
        #pragma unroll
        for (int i = 0; i < 4; i++) {
            int c = tid + i * 256;
            int key = c >> 4;
            int dblk = (c & 15) ^ (key & 7);
            char* ldsK = (char*)sK + (size_t)(i * 256 + w * 64) * 16;
            gl_lds16(Kg + (rowbase + k0 + key) * EMB + hoff + dblk * 8, ldsK);
        }
        // stage V transposed [d][key] (scatter -> VGPR path)
        #pragma unroll
        for (int i = 0; i < 4; i++) {
            int c = tid + i * 256;
            int key = c & 63, d0 = (c >> 6) * 8;
            int4 v = *reinterpret_cast<const int4*>(Vg + (rowbase + k0 + key) * EMB + hoff + d0);
            unsigned short tmp[8];
            *reinterpret_cast<int4*>(tmp) = v;
            #pragma unroll
            for (int j = 0; j < 8; j++) sVt[d0 + j][key] = tmp[j];
        }
        __syncthreads();

        // S^T = K Q^T : 64 keys x 16 q; A = K frag, B = Q frag.
        // sc[ni]: lane holds S^T[key=ni*16+quad*4+r][q=col]
        floatx4 sc[4];
        #pragma unroll
        for (int ni = 0; ni < 4; ni++) {
            #pragma unroll
            for (int r = 0; r < 4; r++) sc[ni][r] = 0.0f;
            #pragma unroll
            for (int ks = 0; ks < 4; ks++) {
                int u = (ni*16 + col) * 16 + (((ks*4 + quad) ^ (col & 7)));
                bf16x8 kf = *reinterpret_cast<const bf16x8*>(&sK[u * 8]);
                sc[ni] = __builtin_amdgcn_mfma_f32_16x16x32_bf16(kf, qf[ks], sc[ni], 0, 0, 0);
            }
        }

        // causal mask: only the diagonal tile has masked entries
        if (kt == qb) {
            #pragma unroll
            for (int ni = 0; ni < 4; ni++)
                #pragma unroll
                for (int r = 0; r < 4; r++) {
                    int keyl = ni*16 + quad*4 + r;
                    if (keyl > tmask) sc[ni][r] = -1e30f;
                }
        }

        // per-lane online softmax over this lane's q column
        float mx = -1e30f;
        #pragma unroll
        for (int ni = 0; ni < 4; ni++)
            #pragma unroll
            for (int r = 0; r < 4; r++) mx = fmaxf(mx, sc[ni][r]);
        mx = fmaxf(mx, __shfl_xor(mx, 16));
        mx = fmaxf(mx, __shfl_xor(mx, 32));
        float mnew  = fmaxf(m_i, mx);
        float alpha = __expf((m_i - mnew) * scl);
        float msc   = mnew * scl;
        float rsum  = 0.0f;
        #pragma unroll
        for (int ni = 0; ni < 4; ni++) {
            ushort4 pk;
            float p0 = __expf(sc[ni][0] * scl - msc);
            float p1 = __expf(sc[ni][1] * scl - msc);
            float p2 = __expf(sc[ni][2] * scl - msc);
            float p3 = __expf(sc[ni][3] * scl - msc);
            rsum += (p0 + p1) + (p2 + p3);
            pk.x = f2bf(p0); pk.y = f2bf(p1); pk.z = f2bf(p2); pk.w = f2bf(p3);
            // P[q=col][key=ni*16+quad*4 .. +3], one b64
            *reinterpret_cast<ushort4*>(&sPw[col*72 + ni*16 + quad*4]) = pk;
        }
        rsum += __shfl_xor(rsum, 16);
        rsum += __shfl_xor(rsum, 32);
        l_i = l_i * alpha + rsum;
        m_i = mnew;
        #pragma unroll
        for (int ni = 0; ni < 8; ni++)
            #pragma unroll
            for (int r = 0; r < 4; r++) oacc[ni][r] *= alpha;
        // no barrier: sP[w] is wave-private; lgkmcnt orders intra-wave LDS

        // O^T += V^T P^T : A = V^T from sVt, B = P^T from sP (b128 reads)
        bf16x8 pf[2];
        #pragma unroll
        for (int ks = 0; ks < 2; ks++)
            pf[ks] = *reinterpret_cast<const bf16x8*>(&sPw[col*72 + ks*32 + quad*8]);
        #pragma unroll
        for (int ni = 0; ni < 8; ni++) {
            #pragma unroll
            for (int ks = 0; ks < 2; ks++) {
                bf16x8 vf = *reinterpret_cast<const bf16x8*>(&sVt[ni*16 + col][ks*32 + quad*8]);
                oacc[ni] = __builtin_amdgcn_mfma_f32_16x16x32_bf16(vf, pf[ks], oacc[ni], 0, 0, 0);
            }
        }
        __syncthreads();  // before next tile overwrites sK/sVt
    }

    // normalize, write ctx[b, q, h*128 + d]; lane: q=qg, d=ni*16+quad*4+r
    float inv = 1.0f / l_i;
    #pragma unroll
    for (int ni = 0; ni < 8; ni++) {
        ushort4 o4;
        o4.x = f2bf(oacc[ni][0] * inv);
        o4.y = f2bf(oacc[ni][1] * inv);
        o4.z = f2bf(oacc[ni][2] * inv);
        o4.w = f2bf(oacc[ni][3] * inv);
        *reinterpret_cast<ushort4*>(O + (rowbase + qg) * EMB + hoff + ni*16 + quad*4) = o4;
    }
}

extern "C" void kernel_launch(void* const* d_in, const int* in_sizes, int n_in,
                              void* d_out, int out_size, void* d_ws, size_t ws_size,
                              hipStream_t stream)
{
    const float* x  = (const float*)d_in[0];
    const float* Wq = (const float*)d_in[1];
    const float* Wk = (const float*)d_in[2];
    const float* Wv = (const float*)d_in[3];
    const float* Wo = (const float*)d_in[4];
    const float* bo = (const float*)d_in[5];
    float* out = (float*)d_out;

    unsigned short* ws = (unsigned short*)d_ws;
    const size_t XN = (size_t)MTOT * EMB;   // 16,777,216
    const size_t WN = (size_t)EMB * EMB;    //  4,194,304
    unsigned short* xb  = ws;
    unsigned short* wqb = xb  + XN;
    unsigned short* wkb = wqb + WN;
    unsigned short* wvb = wkb + WN;
    unsigned short* wob = wvb + WN;
    unsigned short* qb  = wob + WN;
    unsigned short* kb  = qb  + XN;
    unsigned short* vb  = kb  + XN;
    unsigned short* ctx = xb;  // alias: xb dead after the 3 QKV GEMMs

    cast_kernel<<<(int)(XN/4/256), 256, 0, stream>>>(x,  xb,  (int)(XN/4));
    cast_kernel<<<(int)(WN/4/256), 256, 0, stream>>>(Wq, wqb, (int)(WN/4));
    cast_kernel<<<(int)(WN/4/256), 256, 0, stream>>>(Wk, wkb, (int)(WN/4));
    cast_kernel<<<(int)(WN/4/256), 256, 0, stream>>>(Wv, wvb, (int)(WN/4));
    cast_kernel<<<(int)(WN/4/256), 256, 0, stream>>>(Wo, wob, (int)(WN/4));

    dim3 ggrid(EMB / 128, MTOT / 128);  // (16, 64)
    gemm_bt<false><<<ggrid, 256, 0, stream>>>(xb, wqb, qb, nullptr, MTOT, EMB, EMB);
    gemm_bt<false><<<ggrid, 256, 0, stream>>>(xb, wkb, kb, nullptr, MTOT, EMB, EMB);
    gemm_bt<false><<<ggrid, 256, 0, stream>>>(xb, wvb, vb, nullptr, MTOT, EMB, EMB);

    flash_attn<<<dim3(SEQ / 64, 16, 4), 256, 0, stream>>>(qb, kb, vb, ctx);

    gemm_bt<true><<<ggrid, 256, 0, stream>>>(ctx, wob, out, bo, MTOT, EMB, EMB);
}

// Round 5
// 716.852 us; speedup vs baseline: 1.4402x; 1.1105x over previous
//
#include <hip/hip_runtime.h>
#include <math.h>

#define EMB 2048
#define HD 128
#define SEQ 2048
#define MTOT 8192   // B*S

typedef __bf16 bf16x8 __attribute__((ext_vector_type(8)));
typedef float floatx4 __attribute__((ext_vector_type(4)));

__device__ __forceinline__ unsigned short f2bf(float f) {
    unsigned u = __float_as_uint(f);
    return (unsigned short)((u + 0x7FFFu + ((u >> 16) & 1u)) >> 16);  // RNE
}

// async global->LDS, 16B per lane. LDS dest must be wave-uniform base + lane*16.
__device__ __forceinline__ void gl_lds16(const void* g, void* lds) {
    __builtin_amdgcn_global_load_lds(
        (const __attribute__((address_space(1))) unsigned int*)g,
        (__attribute__((address_space(3))) unsigned int*)lds,
        16, 0, 0);
}

// ---------------- fp32 -> bf16 cast, 4 elems/thread ----------------
__global__ void cast_kernel(const float* __restrict__ src,
                            unsigned short* __restrict__ dst, int n4) {
    int i = blockIdx.x * blockDim.x + threadIdx.x;
    if (i >= n4) return;
    float4 v = reinterpret_cast<const float4*>(src)[i];
    ushort4 o;
    o.x = f2bf(v.x); o.y = f2bf(v.y); o.z = f2bf(v.z); o.w = f2bf(v.w);
    reinterpret_cast<ushort4*>(dst)[i] = o;
}

// ---------------- C[M,N] = A[M,K] * Bw[N,K]^T  (bf16 MFMA) ----------------
// 128x128 block tile, 4 waves (2x2), each wave 64x64 via 4x4 16x16x32 MFMAs.
// Staging via global_load_lds width=16 (m97 pattern). Unchanged (verified).
template<bool OUT_F32>
__global__ __launch_bounds__(256, 2)
void gemm_bt(const unsigned short* __restrict__ A,
             const unsigned short* __restrict__ Bw,
             void* __restrict__ Cout,
             const float* __restrict__ bias,
             int M, int N, int K)
{
    __shared__ __align__(16) unsigned short sA[128][32];
    __shared__ __align__(16) unsigned short sB[128][32];

    const int tid  = threadIdx.x;
    const int lane = tid & 63;
    const int wave = tid >> 6;
    const int wm = wave >> 1, wn = wave & 1;
    const int col  = lane & 15;
    const int quad = lane >> 4;

    const int m0 = blockIdx.y * 128;
    const int n0 = blockIdx.x * 128;

    floatx4 acc[4][4];
    #pragma unroll
    for (int i = 0; i < 4; i++)
        #pragma unroll
        for (int j = 0; j < 4; j++)
            #pragma unroll
            for (int r = 0; r < 4; r++) acc[i][j][r] = 0.0f;

    for (int k0 = 0; k0 < K; k0 += 32) {
        #pragma unroll
        for (int i = 0; i < 2; i++) {
            int c = tid + i * 256;
            int row = c >> 2, cc = (c & 3) * 8;
            char* ldsA = (char*)sA + (size_t)(i * 256 + wave * 64) * 16;
            char* ldsB = (char*)sB + (size_t)(i * 256 + wave * 64) * 16;
            gl_lds16(A  + (size_t)(m0 + row) * K + k0 + cc, ldsA);
            gl_lds16(Bw + (size_t)(n0 + row) * K + k0 + cc, ldsB);
        }
        __syncthreads();

        bf16x8 af[4], bfr[4];
        #pragma unroll
        for (int mi = 0; mi < 4; mi++)
            af[mi] = *reinterpret_cast<const bf16x8*>(&sA[wm*64 + mi*16 + col][quad*8]);
        #pragma unroll
        for (int ni = 0; ni < 4; ni++)
            bfr[ni] = *reinterpret_cast<const bf16x8*>(&sB[wn*64 + ni*16 + col][quad*8]);

        #pragma unroll
        for (int mi = 0; mi < 4; mi++)
            #pragma unroll
            for (int ni = 0; ni < 4; ni++)
                acc[mi][ni] = __builtin_amdgcn_mfma_f32_16x16x32_bf16(
                                  af[mi], bfr[ni], acc[mi][ni], 0, 0, 0);
        __syncthreads();
    }

    #pragma unroll
    for (int mi = 0; mi < 4; mi++) {
        #pragma unroll
        for (int ni = 0; ni < 4; ni++) {
            #pragma unroll
            for (int r = 0; r < 4; r++) {
                int row = m0 + wm*64 + mi*16 + quad*4 + r;
                int cg  = n0 + wn*64 + ni*16 + col;
                float v = acc[mi][ni][r];
                if (OUT_F32) {
                    float bb = bias ? bias[cg] : 0.0f;
                    reinterpret_cast<float*>(Cout)[(size_t)row * N + cg] = v + bb;
                } else {
                    reinterpret_cast<unsigned short*>(Cout)[(size_t)row * N + cg] = f2bf(v);
                }
            }
        }
    }
}

// ---------------- causal flash attention, S^T formulation, 128-q blocks ----
// grid (qsb=16, h=16, b=4); block 256 = 4 waves; wave owns 32 q rows as two
// 16-col groups processed with SHARED kf/vf fragments (K/V staged once per
// 128 q). Softmax per-lane (one q per lane per group) + 2 shfls.
__global__ __launch_bounds__(256, 2)
void flash_attn(const unsigned short* __restrict__ Q,
                const unsigned short* __restrict__ Kg,
                const unsigned short* __restrict__ Vg,
                unsigned short* __restrict__ O)
{
    // sK storage: 16B unit u = key*16 + (dblk ^ (key&7)), dblk = d/8. 16 KB.
    __shared__ __align__(16) unsigned short sK[64 * 128];
    __shared__ __align__(16) unsigned short sVt[128][72];   // [d][key], padded
    __shared__ __align__(16) unsigned short sP[4][16 * 72]; // [q][key], per-wave, reused per group

    const int tid  = threadIdx.x;
    const int lane = tid & 63;
    const int w    = tid >> 6;
    const int col  = lane & 15;
    const int quad = lane >> 4;

    const int qsb = (SEQ / 128 - 1) - blockIdx.x;   // heavy blocks first
    const int h   = blockIdx.y;
    const int b   = blockIdx.z;

    const int qbase = qsb * 128;
    const size_t rowbase = (size_t)b * SEQ;
    const int hoff = h * HD;

    // group g: this lane's q row = qbase + w*32 + g*16 + col
    const int qg0 = qbase + w*32 + col;        // g=0
    const int qg1 = qg0 + 16;                  // g=1

    // Q fragments (B-operand for S^T): lane holds Q[q][d=ks*32+quad*8+j]
    bf16x8 qf[2][4];
    {
        const unsigned short* qr0 = Q + (rowbase + qg0) * EMB + hoff;
        const unsigned short* qr1 = Q + (rowbase + qg1) * EMB + hoff;
        #pragma unroll
        for (int ks = 0; ks < 4; ks++) {
            qf[0][ks] = *reinterpret_cast<const bf16x8*>(qr0 + ks*32 + quad*8);
            qf[1][ks] = *reinterpret_cast<const bf16x8*>(qr1 + ks*32 + quad*8);
        }
    }

    // O^T accumulators: lane holds O^T[d=ni*16+quad*4+r][q]
    floatx4 oacc[2][8];
    #pragma unroll
    for (int g = 0; g < 2; g++)
        #pragma unroll
        for (int ni = 0; ni < 8; ni++)
            #pragma unroll
            for (int r = 0; r < 4; r++) oacc[g][ni][r] = 0.0f;
    float m_i[2] = {-1e30f, -1e30f}, l_i[2] = {0.0f, 0.0f};

    const float scl = 0.08838834764831845f;  // 1/sqrt(128)
    unsigned short* sPw = sP[w];

    const int ktmax = qbase / 64 + 1;   // last key tile overlapping q range
    for (int kt = 0; kt <= ktmax; kt++) {
        const int k0 = kt * 64;
        // ---- stage K tile via glds; chunk c -> LDS byte c*16, swizzled source
        #pragma unroll
        for (int i = 0; i < 4; i++) {
            int c = tid + i * 256;
            int key = c >> 4;
            int dblk = (c & 15) ^ (key & 7);
            char* ldsK = (char*)sK + (size_t)(i * 256 + w * 64) * 16;
            gl_lds16(Kg + (rowbase + k0 + key) * EMB + hoff + dblk * 8, ldsK);
        }
        // ---- stage V transposed: 4-key x 8-d superchunk per thread, b64 writes
        {
            int k4 = (tid & 15) * 4;
            int d0 = (tid >> 4) * 8;
            unsigned short va[4][8];
            #pragma unroll
            for (int kk = 0; kk < 4; kk++)
                *reinterpret_cast<int4*>(va[kk]) =
                    *reinterpret_cast<const int4*>(Vg + (rowbase + k0 + k4 + kk) * EMB + hoff + d0);
            #pragma unroll
            for (int j = 0; j < 8; j++) {
                ushort4 o;
                o.x = va[0][j]; o.y = va[1][j]; o.z = va[2][j]; o.w = va[3][j];
                *reinterpret_cast<ushort4*>(&sVt[d0 + j][k4]) = o;
            }
        }
        __syncthreads();

        // wave-uniform activity gate (alignment => both groups share it)
        if (k0 <= qbase + w*32 + 31) {
            // ---- S^T = K Q^T for both groups, kf shared
            floatx4 sc[2][4];
            #pragma unroll
            for (int g = 0; g < 2; g++)
                #pragma unroll
                for (int ni = 0; ni < 4; ni++)
                    #pragma unroll
                    for (int r = 0; r < 4; r++) sc[g][ni][r] = 0.0f;
            #pragma unroll
            for (int ni = 0; ni < 4; ni++) {
                #pragma unroll
                for (int ks = 0; ks < 4; ks++) {
                    int u = (ni*16 + col) * 16 + ((ks*4 + quad) ^ (col & 7));
                    bf16x8 kf = *reinterpret_cast<const bf16x8*>(&sK[u * 8]);
                    sc[0][ni] = __builtin_amdgcn_mfma_f32_16x16x32_bf16(kf, qf[0][ks], sc[0][ni], 0, 0, 0);
                    sc[1][ni] = __builtin_amdgcn_mfma_f32_16x16x32_bf16(kf, qf[1][ks], sc[1][ni], 0, 0, 0);
                }
            }

            const bool need_mask = (k0 + 63 > qbase + w*32);
            bf16x8 pf[2][2];

            #pragma unroll
            for (int g = 0; g < 2; g++) {
                const int qg = (g == 0) ? qg0 : qg1;
                if (need_mask) {
                    #pragma unroll
                    for (int ni = 0; ni < 4; ni++)
                        #pragma unroll
                        for (int r = 0; r < 4; r++) {
                            int key = k0 + ni*16 + quad*4 + r;
                            if (key > qg) sc[g][ni][r] = -1e30f;
                        }
                }
                // per-lane online softmax over this lane's q column
                float mx = -1e30f;
                #pragma unroll
                for (int ni = 0; ni < 4; ni++)
                    #pragma unroll
                    for (int r = 0; r < 4; r++) mx = fmaxf(mx, sc[g][ni][r]);
                mx = fmaxf(mx, __shfl_xor(mx, 16));
                mx = fmaxf(mx, __shfl_xor(mx, 32));
                float mnew  = fmaxf(m_i[g], mx);
                float alpha = __expf((m_i[g] - mnew) * scl);
                float msc   = mnew * scl;
                float rsum  = 0.0f;
                #pragma unroll
                for (int ni = 0; ni < 4; ni++) {
                    float p0 = __expf(sc[g][ni][0] * scl - msc);
                    float p1 = __expf(sc[g][ni][1] * scl - msc);
                    float p2 = __expf(sc[g][ni][2] * scl - msc);
                    float p3 = __expf(sc[g][ni][3] * scl - msc);
                    rsum += (p0 + p1) + (p2 + p3);
                    ushort4 pk;
                    pk.x = f2bf(p0); pk.y = f2bf(p1); pk.z = f2bf(p2); pk.w = f2bf(p3);
                    *reinterpret_cast<ushort4*>(&sPw[col*72 + ni*16 + quad*4]) = pk;
                }
                rsum += __shfl_xor(rsum, 16);
                rsum += __shfl_xor(rsum, 32);
                l_i[g] = l_i[g] * alpha + rsum;
                m_i[g] = mnew;
                #pragma unroll
                for (int ni = 0; ni < 8; ni++)
                    #pragma unroll
                    for (int r = 0; r < 4; r++) oacc[g][ni][r] *= alpha;
                // read back P^T fragments for this group (in-order DS per wave
                // makes the sP reuse across groups safe; verified R3/R4)
                #pragma unroll
                for (int ks = 0; ks < 2; ks++)
                    pf[g][ks] = *reinterpret_cast<const bf16x8*>(&sPw[col*72 + ks*32 + quad*8]);
            }

            // ---- O^T += V^T P^T, vf shared across groups
            #pragma unroll
            for (int ni = 0; ni < 8; ni++) {
                #pragma unroll
                for (int ks = 0; ks < 2; ks++) {
                    bf16x8 vf = *reinterpret_cast<const bf16x8*>(&sVt[ni*16 + col][ks*32 + quad*8]);
                    oacc[0][ni] = __builtin_amdgcn_mfma_f32_16x16x32_bf16(vf, pf[0][ks], oacc[0][ni], 0, 0, 0);
                    oacc[1][ni] = __builtin_amdgcn_mfma_f32_16x16x32_bf16(vf, pf[1][ks], oacc[1][ni], 0, 0, 0);
                }
            }
        }
        __syncthreads();  // before next tile overwrites sK/sVt
    }

    // normalize, write ctx[b, q, h*128 + d]
    #pragma unroll
    for (int g = 0; g < 2; g++) {
        const int qg = (g == 0) ? qg0 : qg1;
        float inv = 1.0f / l_i[g];
        #pragma unroll
        for (int ni = 0; ni < 8; ni++) {
            ushort4 o4;
            o4.x = f2bf(oacc[g][ni][0] * inv);
            o4.y = f2bf(oacc[g][ni][1] * inv);
            o4.z = f2bf(oacc[g][ni][2] * inv);
            o4.w = f2bf(oacc[g][ni][3] * inv);
            *reinterpret_cast<ushort4*>(O + (rowbase + qg) * EMB + hoff + ni*16 + quad*4) = o4;
        }
    }
}

extern "C" void kernel_launch(void* const* d_in, const int* in_sizes, int n_in,
                              void* d_out, int out_size, void* d_ws, size_t ws_size,
                              hipStream_t stream)
{
    const float* x  = (const float*)d_in[0];
    const float* Wq = (const float*)d_in[1];
    const float* Wk = (const float*)d_in[2];
    const float* Wv = (const float*)d_in[3];
    const float* Wo = (const float*)d_in[4];
    const float* bo = (const float*)d_in[5];
    float* out = (float*)d_out;

    unsigned short* ws = (unsigned short*)d_ws;
    const size_t XN = (size_t)MTOT * EMB;   // 16,777,216
    const size_t WN = (size_t)EMB * EMB;    //  4,194,304
    unsigned short* xb  = ws;
    unsigned short* wqb = xb  + XN;
    unsigned short* wkb = wqb + WN;
    unsigned short* wvb = wkb + WN;
    unsigned short* wob = wvb + WN;
    unsigned short* qb  = wob + WN;
    unsigned short* kb  = qb  + XN;
    unsigned short* vb  = kb  + XN;
    unsigned short* ctx = xb;  // alias: xb dead after the 3 QKV GEMMs

    cast_kernel<<<(int)(XN/4/256), 256, 0, stream>>>(x,  xb,  (int)(XN/4));
    cast_kernel<<<(int)(WN/4/256), 256, 0, stream>>>(Wq, wqb, (int)(WN/4));
    cast_kernel<<<(int)(WN/4/256), 256, 0, stream>>>(Wk, wkb, (int)(WN/4));
    cast_kernel<<<(int)(WN/4/256), 256, 0, stream>>>(Wv, wvb, (int)(WN/4));
    cast_kernel<<<(int)(WN/4/256), 256, 0, stream>>>(Wo, wob, (int)(WN/4));

    dim3 ggrid(EMB / 128, MTOT / 128);  // (16, 64)
    gemm_bt<false><<<ggrid, 256, 0, stream>>>(xb, wqb, qb, nullptr, MTOT, EMB, EMB);
    gemm_bt<false><<<ggrid, 256, 0, stream>>>(xb, wkb, kb, nullptr, MTOT, EMB, EMB);
    gemm_bt<false><<<ggrid, 256, 0, stream>>>(xb, wvb, vb, nullptr, MTOT, EMB, EMB);

    flash_attn<<<dim3(SEQ / 128, 16, 4), 256, 0, stream>>>(qb, kb, vb, ctx);

    gemm_bt<true><<<ggrid, 256, 0, stream>>>(ctx, wob, out, bo, MTOT, EMB, EMB);
}